// Round 6
// baseline (890.163 us; speedup 1.0000x reference)
//
#include <hip/hip_runtime.h>
#include <hip/hip_bf16.h>
#include <cstdint>

#define DM 2048
#define DF 8192

typedef int v4i __attribute__((ext_vector_type(4)));
typedef int v16i __attribute__((ext_vector_type(16)));
typedef short v8s __attribute__((ext_vector_type(8)));

__device__ __forceinline__ float silu_f(float y) {
  return y * (1.0f / (1.0f + expf(-y)));
}

__device__ __forceinline__ void gload_lds16(const void* g, void* l) {
  __builtin_amdgcn_global_load_lds(
      (const __attribute__((address_space(1))) void*)g,
      (__attribute__((address_space(3))) void*)l, 16, 0, 0);
}

// ---- stage 1: sum |w| partials ----
__global__ __launch_bounds__(256) void abs_sum_k(const float* __restrict__ w,
                                                 float* __restrict__ partial) {
  const int t = threadIdx.x;
  const float4* wp = (const float4*)w;
  const long base = (long)blockIdx.x * 4096;
  float s = 0.f;
#pragma unroll
  for (int i = 0; i < 16; ++i) {
    float4 v = wp[base + i * 256 + t];
    s += fabsf(v.x) + fabsf(v.y) + fabsf(v.z) + fabsf(v.w);
  }
#pragma unroll
  for (int d = 1; d < 64; d <<= 1) s += __shfl_xor(s, d, 64);
  __shared__ float wsum[4];
  if ((t & 63) == 0) wsum[t >> 6] = s;
  __syncthreads();
  if (t == 0) partial[blockIdx.x] = (wsum[0] + wsum[1]) + (wsum[2] + wsum[3]);
}

// ---- stage 2: finalize weight scales ----
__global__ __launch_bounds__(256) void finalize_scales_k(const float* __restrict__ p1,
                                                         const float* __restrict__ p2,
                                                         float* __restrict__ sc) {
  const float* p = (blockIdx.x == 0) ? p1 : p2;
  const int t = threadIdx.x;
  float s = (p[t] + p[t + 256]) + (p[t + 512] + p[t + 768]);
#pragma unroll
  for (int d = 1; d < 64; d <<= 1) s += __shfl_xor(s, d, 64);
  __shared__ float wsum[4];
  if ((t & 63) == 0) wsum[t >> 6] = s;
  __syncthreads();
  if (t == 0) {
    float total = (wsum[0] + wsum[1]) + (wsum[2] + wsum[3]);
    float mean = total * (1.0f / 16777216.0f);
    float c = fmaxf(mean, 1e-5f);
    sc[blockIdx.x * 2 + 0] = 1.0f / c;
    sc[blockIdx.x * 2 + 1] = c;
  }
}

// ---- ternary weight quantization ----
__global__ __launch_bounds__(256) void tern_quant_k(const float* __restrict__ w,
                                                    int8_t* __restrict__ wq,
                                                    const float* __restrict__ scp) {
  const float s = scp[0];
  const long i = (long)blockIdx.x * 256 + threadIdx.x;
  float4 v = ((const float4*)w)[i];
  int q0 = (int)rintf(v.x * s); q0 = q0 < -1 ? -1 : (q0 > 1 ? 1 : q0);
  int q1 = (int)rintf(v.y * s); q1 = q1 < -1 ? -1 : (q1 > 1 ? 1 : q1);
  int q2 = (int)rintf(v.z * s); q2 = q2 < -1 ? -1 : (q2 > 1 ? 1 : q2);
  int q3 = (int)rintf(v.w * s); q3 = q3 < -1 ? -1 : (q3 > 1 ? 1 : q3);
  ((int*)wq)[i] = (q0 & 255) | ((q1 & 255) << 8) | ((q2 & 255) << 16) | ((q3 & 255) << 24);
}

// ---- per-token activation quant of x ----
__global__ __launch_bounds__(256) void act_quant_x_k(const float* __restrict__ x,
                                                     int8_t* __restrict__ xq,
                                                     float* __restrict__ inv_sx) {
  const int t = threadIdx.x;
  const long row = blockIdx.x;
  const float4* xr = (const float4*)(x + row * DM);
  float4 v0 = xr[t * 2], v1 = xr[t * 2 + 1];
  float m = fmaxf(fmaxf(fmaxf(fabsf(v0.x), fabsf(v0.y)), fmaxf(fabsf(v0.z), fabsf(v0.w))),
                  fmaxf(fmaxf(fabsf(v1.x), fabsf(v1.y)), fmaxf(fabsf(v1.z), fabsf(v1.w))));
#pragma unroll
  for (int d = 1; d < 64; d <<= 1) m = fmaxf(m, __shfl_xor(m, d, 64));
  __shared__ float wm[4];
  if ((t & 63) == 0) wm[t >> 6] = m;
  __syncthreads();
  m = fmaxf(fmaxf(wm[0], wm[1]), fmaxf(wm[2], wm[3]));
  const float scale = 127.0f / fmaxf(m, 1e-5f);
  if (t == 0) inv_sx[row] = 1.0f / scale;
  float vv[8] = {v0.x, v0.y, v0.z, v0.w, v1.x, v1.y, v1.z, v1.w};
  int q[8];
#pragma unroll
  for (int j = 0; j < 8; ++j) {
    int qq = (int)rintf(vv[j] * scale);
    q[j] = qq < -128 ? -128 : (qq > 127 ? 127 : qq);
  }
  int lo = (q[0] & 255) | ((q[1] & 255) << 8) | ((q[2] & 255) << 16) | ((q[3] & 255) << 24);
  int hi = (q[4] & 255) | ((q[5] & 255) << 8) | ((q[6] & 255) << 16) | ((q[7] & 255) << 24);
  ((int2*)(xq + row * DM))[t] = make_int2(lo, hi);
}

// ---- read one ks-slice of fragments (8 x ds_read_b128) ----
__device__ __forceinline__ void rdset(const uint8_t* Ap, const uint8_t* Bp,
                                      int rbase, int cks,
                                      v4i (&Af)[4], v4i (&Bf)[4]) {
#pragma unroll
  for (int q = 0; q < 4; ++q) {
    Af[q] = *(const v4i*)(Ap + q * 4096 + rbase + cks);
    Bf[q] = *(const v4i*)(Bp + q * 4096 + rbase + cks);
  }
}

__device__ __forceinline__ void mfma16(const v4i (&Af)[4], const v4i (&Bf)[4],
                                       v16i (&acc)[4][4]) {
#pragma unroll
  for (int mt = 0; mt < 4; ++mt)
#pragma unroll
    for (int nt = 0; nt < 4; ++nt)
      acc[mt][nt] = __builtin_amdgcn_mfma_i32_32x32x32_i8(Af[mt], Bf[nt], acc[mt][nt], 0, 0, 0);
}

// ---- int8 GEMM, 256x256 tile, BK=128B, 4 waves (2x2), wave-tile 128x128 ----
// LDS layout per 4KB quarter (32 rows x 128B): rows r and r+16 share a 256B
// line: byte(r,j) = (r&15)*256 + (r>>4)*128 + ((j ^ (r&7))<<4)  -- makes every
// fragment ds_read_b128 bank-identical to the proven-conflict-free gemm8
// pattern (16-row groups, XOR col phases). Staging sources carry the inverse
// map (rule #21). Single wave/SIMD; T19 sched_group_barrier chain interleaves
// {DS_READ 2, MFMA 4} so one wave feeds both pipes; all 16 stage-issues at
// K-tile start so the end-of-tile drain is free.
template <int K, int N, int EPI>
__global__ __launch_bounds__(256, 1) void gemm4_i8_k(
    const int8_t* __restrict__ A, const int8_t* __restrict__ B,
    const float* __restrict__ rowInv, const float* __restrict__ invswp,
    short* __restrict__ Y16, float* __restrict__ rowmaxP,
    float* __restrict__ Out) {
  constexpr int NT = K / 128;
  constexpr int NBX = N / 256;
  constexpr int NSTX = NBX / 4;   // supertile = 8by x 4bx = 32 blocks
  __shared__ __align__(16) uint8_t lds[131072];

  const int t = threadIdx.x;
  const int wave = t >> 6;
  const int lane = t & 63;
  const int wr = wave >> 1, wc = wave & 1;   // 2x2 waves, 128x128 each
  const int l31 = lane & 31, kg = lane >> 5;

  const int cpx = (int)gridDim.x >> 3;
  const int bid0 = blockIdx.x;
  const int bid = (bid0 & 7) * cpx + (bid0 >> 3);
  const int st = bid >> 5, u = bid & 31;
  const int by = (st / NSTX) * 8 + (u >> 2);
  const int bx = (st % NSTX) * 4 + (u & 3);
  const long arow0 = (long)by * 256;
  const long bcol0 = (long)bx * 256;

  // staging inverse map: wave w's 1KB slot of each quarter holds
  // r15 = 4w + (lane>>4), rh = (lane>>3)&1, slot = lane&7
  const int s_r15 = wave * 4 + (lane >> 4);
  const int s_row = s_r15 + 16 * ((lane >> 3) & 1);
  const int s_j = (lane & 7) ^ (s_r15 & 7);
  const long stg_off = (long)s_row * K + (s_j << 4);

  const int8_t* psrc0 = A + arow0 * K;                 // A rows 0-127
  const int8_t* psrc1 = psrc0 + (long)128 * K;         // A rows 128-255
  const int8_t* psrc2 = B + bcol0 * K;                 // B rows 0-127
  const int8_t* psrc3 = psrc2 + (long)128 * K;         // B rows 128-255

  // fragment read constants: lane wants row l31, j = ks*2 + kg
  const int rbase = (lane & 15) * 256 + ((lane >> 4) & 1) * 128;
  const int c0 = ((0 | kg) ^ (lane & 7)) << 4;
  const int c1 = ((2 | kg) ^ (lane & 7)) << 4;
  const int c2 = ((4 | kg) ^ (lane & 7)) << 4;
  const int c3 = ((6 | kg) ^ (lane & 7)) << 4;

  v16i acc[4][4] = {};
  v4i SA0[4], SB0[4], SA1[4], SB1[4];

#define STAGEP(kk_, part_, ps_)                                            \
  do {                                                                     \
    if ((kk_) < NT) {                                                      \
      uint8_t* d = lds + (((kk_) & 1) << 16) + ((part_) << 14) + (wave << 10); \
      const int8_t* s = (ps_) + (((long)(kk_)) << 7) + stg_off;            \
      gload_lds16(s, d);                                                   \
      gload_lds16(s + 32 * (long)K, d + 4096);                             \
      gload_lds16(s + 64 * (long)K, d + 8192);                             \
      gload_lds16(s + 96 * (long)K, d + 12288);                            \
    }                                                                      \
  } while (0)

#define SGB(m_, n_) __builtin_amdgcn_sched_group_barrier((m_), (n_), 0)

  STAGEP(0, 0, psrc0); STAGEP(0, 1, psrc1);
  STAGEP(0, 2, psrc2); STAGEP(0, 3, psrc3);
  __syncthreads();

  for (int kt = 0; kt < NT; ++kt) {
    const uint8_t* Ap = lds + ((kt & 1) << 16) + (wr << 14);
    const uint8_t* Bp = lds + ((kt & 1) << 16) + ((2 + wc) << 14);

    rdset(Ap, Bp, rbase, c0, SA0, SB0);
    STAGEP(kt + 1, 0, psrc0);
    STAGEP(kt + 1, 1, psrc1);
    STAGEP(kt + 1, 2, psrc2);
    STAGEP(kt + 1, 3, psrc3);
    rdset(Ap, Bp, rbase, c1, SA1, SB1);
    mfma16(SA0, SB0, acc);               // ks0
    rdset(Ap, Bp, rbase, c2, SA0, SB0);
    mfma16(SA1, SB1, acc);               // ks1
    rdset(Ap, Bp, rbase, c3, SA1, SB1);
    mfma16(SA0, SB0, acc);               // ks2
    mfma16(SA1, SB1, acc);               // ks3

    // desired emission: S0 reads + stage burst, then {DS2,MFMA4} interleave
    SGB(0x100, 8);                        // ks0 fragment reads
    SGB(0x20, 16);                        // 16 global_load_lds
    SGB(0x100, 2); SGB(8, 4); SGB(0x100, 2); SGB(8, 4);
    SGB(0x100, 2); SGB(8, 4); SGB(0x100, 2); SGB(8, 4);   // ks1 reads | MFMA ks0
    SGB(0x100, 2); SGB(8, 4); SGB(0x100, 2); SGB(8, 4);
    SGB(0x100, 2); SGB(8, 4); SGB(0x100, 2); SGB(8, 4);   // ks2 reads | MFMA ks1
    SGB(0x100, 2); SGB(8, 4); SGB(0x100, 2); SGB(8, 4);
    SGB(0x100, 2); SGB(8, 4); SGB(0x100, 2); SGB(8, 4);   // ks3 reads | MFMA ks2
    SGB(8, 16);                                           // MFMA ks3
    __syncthreads();
  }

  const float invsw = invswp[0];
  if constexpr (EPI == 1) {
    // Phase A: clamp + stage y16 to LDS short[256][256], byte XOR (row&7)<<4
#pragma unroll
    for (int mt = 0; mt < 4; ++mt)
#pragma unroll
      for (int nt = 0; nt < 4; ++nt)
#pragma unroll
        for (int r = 0; r < 16; ++r) {
          const int row = wr * 128 + mt * 32 + (r & 3) + 8 * (r >> 2) + 4 * kg;
          const int col = wc * 128 + nt * 32 + l31;
          int yi = acc[mt][nt][r];
          int ys = yi < -32767 ? -32767 : (yi > 32767 ? 32767 : yi);
          *(short*)(lds + ((row * 512 + col * 2) ^ ((row & 7) << 4))) = (short)ys;
        }
    __syncthreads();
    // Phase B: thread t owns row t: silu-rowmax + coalesced stores
    const long grow = arow0 + t;
    const float c1v = rowInv[grow] * invsw;
    float mx = 0.f;
    short* gp = Y16 + grow * (long)DF + bcol0;
#pragma unroll
    for (int i = 0; i < 32; ++i) {
      v8s yv = *(const v8s*)(lds + ((t * 512 + i * 16) ^ ((t & 7) << 4)));
#pragma unroll
      for (int j = 0; j < 8; ++j) mx = fmaxf(mx, fabsf(silu_f((float)yv[j] * c1v)));
      *(v8s*)(gp + i * 8) = yv;
    }
    rowmaxP[grow * NBX + bx] = mx;
  } else {
#pragma unroll
    for (int mt = 0; mt < 4; ++mt)
#pragma unroll
      for (int r = 0; r < 16; ++r) {
        const long grow = arow0 + wr * 128 + mt * 32 + (r & 3) + 8 * (r >> 2) + 4 * kg;
        const float cc = rowInv[grow] * invsw;
#pragma unroll
        for (int nt = 0; nt < 4; ++nt)
          Out[grow * N + bcol0 + wc * 128 + nt * 32 + l31] = (float)acc[mt][nt][r] * cc;
      }
  }
#undef STAGEP
#undef SGB
}

// ---- quantize h per-token from int16 y (16B loads, 8B stores) ----
__global__ __launch_bounds__(256) void quant_h_k(const short* __restrict__ Y16,
                                                 const float* __restrict__ rowmaxP,
                                                 const float* __restrict__ inv_sx,
                                                 const float* __restrict__ sc,
                                                 int8_t* __restrict__ hq,
                                                 float* __restrict__ inv_sh) {
  const int t = threadIdx.x;
  const long row = blockIdx.x;
  __shared__ float smax_s;
  if (t < 64) {
    float m = (t < 32) ? rowmaxP[row * 32 + t] : 0.f;
#pragma unroll
    for (int d = 1; d < 64; d <<= 1) m = fmaxf(m, __shfl_xor(m, d, 64));
    if (t == 0) smax_s = m;
  }
  __syncthreads();
  const float scale = 127.0f / fmaxf(smax_s, 1e-5f);
  if (t == 0) inv_sh[row] = 1.0f / scale;
  const float c1 = inv_sx[row] * sc[1];
  const v8s* yp = (const v8s*)(Y16 + row * DF);
  int2* op = (int2*)(hq + row * DF);
#pragma unroll
  for (int b = 0; b < 4; ++b) {
    v8s s8 = yp[b * 256 + t];
    int q[8];
#pragma unroll
    for (int j = 0; j < 8; ++j) {
      float h = silu_f((float)s8[j] * c1);
      int qq = (int)rintf(h * scale);
      q[j] = qq < -128 ? -128 : (qq > 127 ? 127 : qq);
    }
    int lo = (q[0] & 255) | ((q[1] & 255) << 8) | ((q[2] & 255) << 16) | ((q[3] & 255) << 24);
    int hi = (q[4] & 255) | ((q[5] & 255) << 8) | ((q[6] & 255) << 16) | ((q[7] & 255) << 24);
    op[b * 256 + t] = make_int2(lo, hi);
  }
}

extern "C" void kernel_launch(void* const* d_in, const int* in_sizes, int n_in,
                              void* d_out, int out_size, void* d_ws, size_t ws_size,
                              hipStream_t stream) {
  const float* x = (const float*)d_in[0];
  const float* W1 = (const float*)d_in[1];
  const float* W2 = (const float*)d_in[2];
  float* out = (float*)d_out;

  uint8_t* w = (uint8_t*)d_ws;
  float* sc = (float*)(w + 0);
  float* p1 = (float*)(w + 256);
  float* p2 = (float*)(w + 256 + 4096);
  float* inv_sx = (float*)(w + 8448);
  float* inv_sh = (float*)(w + 8448 + 65536);
  float* rowmaxP = (float*)(w + 8448 + 131072);
  uint8_t* w1q = w + 8448 + 131072 + 4194304;
  uint8_t* w2q = w1q + 16777216;
  uint8_t* xq = w2q + 16777216;
  uint8_t* hq = xq + 33554432;
  short* y16 = (short*)(hq + 134217728);

  abs_sum_k<<<1024, 256, 0, stream>>>(W1, p1);
  abs_sum_k<<<1024, 256, 0, stream>>>(W2, p2);
  finalize_scales_k<<<2, 256, 0, stream>>>(p1, p2, sc);
  tern_quant_k<<<16384, 256, 0, stream>>>(W1, (int8_t*)w1q, sc + 0);
  tern_quant_k<<<16384, 256, 0, stream>>>(W2, (int8_t*)w2q, sc + 2);
  act_quant_x_k<<<16384, 256, 0, stream>>>(x, (int8_t*)xq, inv_sx);
  // GEMM1: [16384,2048] x [8192,2048]^T -> y16 + rowmax partials
  gemm4_i8_k<2048, 8192, 1><<<2048, 256, 0, stream>>>(
      (const int8_t*)xq, (const int8_t*)w1q, inv_sx, sc + 1, y16, rowmaxP, nullptr);
  quant_h_k<<<16384, 256, 0, stream>>>(y16, rowmaxP, inv_sx, sc, (int8_t*)hq, inv_sh);
  // GEMM2: [16384,8192] x [2048,8192]^T -> out
  gemm4_i8_k<8192, 2048, 0><<<512, 256, 0, stream>>>(
      (const int8_t*)hq, (const int8_t*)w2q, inv_sh, sc + 3, nullptr, nullptr, out);
}

// Round 7
// 885.399 us; speedup vs baseline: 1.0054x; 1.0054x over previous
//
#include <hip/hip_runtime.h>
#include <hip/hip_bf16.h>
#include <cstdint>

#define DM 2048
#define DF 8192

typedef int v4i __attribute__((ext_vector_type(4)));
typedef short v8s __attribute__((ext_vector_type(8)));

__device__ __forceinline__ float silu_f(float y) {
  return y * (1.0f / (1.0f + expf(-y)));
}

__device__ __forceinline__ void gload_lds16(const void* g, void* l) {
  __builtin_amdgcn_global_load_lds(
      (const __attribute__((address_space(1))) void*)g,
      (__attribute__((address_space(3))) void*)l, 16, 0, 0);
}

// ---- stage 1: sum |w| partials ----
__global__ __launch_bounds__(256) void abs_sum_k(const float* __restrict__ w,
                                                 float* __restrict__ partial) {
  const int t = threadIdx.x;
  const float4* wp = (const float4*)w;
  const long base = (long)blockIdx.x * 4096;
  float s = 0.f;
#pragma unroll
  for (int i = 0; i < 16; ++i) {
    float4 v = wp[base + i * 256 + t];
    s += fabsf(v.x) + fabsf(v.y) + fabsf(v.z) + fabsf(v.w);
  }
#pragma unroll
  for (int d = 1; d < 64; d <<= 1) s += __shfl_xor(s, d, 64);
  __shared__ float wsum[4];
  if ((t & 63) == 0) wsum[t >> 6] = s;
  __syncthreads();
  if (t == 0) partial[blockIdx.x] = (wsum[0] + wsum[1]) + (wsum[2] + wsum[3]);
}

// ---- stage 2: finalize weight scales ----
__global__ __launch_bounds__(256) void finalize_scales_k(const float* __restrict__ p1,
                                                         const float* __restrict__ p2,
                                                         float* __restrict__ sc) {
  const float* p = (blockIdx.x == 0) ? p1 : p2;
  const int t = threadIdx.x;
  float s = (p[t] + p[t + 256]) + (p[t + 512] + p[t + 768]);
#pragma unroll
  for (int d = 1; d < 64; d <<= 1) s += __shfl_xor(s, d, 64);
  __shared__ float wsum[4];
  if ((t & 63) == 0) wsum[t >> 6] = s;
  __syncthreads();
  if (t == 0) {
    float total = (wsum[0] + wsum[1]) + (wsum[2] + wsum[3]);
    float mean = total * (1.0f / 16777216.0f);
    float c = fmaxf(mean, 1e-5f);
    sc[blockIdx.x * 2 + 0] = 1.0f / c;
    sc[blockIdx.x * 2 + 1] = c;
  }
}

// ---- ternary weight quantization ----
__global__ __launch_bounds__(256) void tern_quant_k(const float* __restrict__ w,
                                                    int8_t* __restrict__ wq,
                                                    const float* __restrict__ scp) {
  const float s = scp[0];
  const long i = (long)blockIdx.x * 256 + threadIdx.x;
  float4 v = ((const float4*)w)[i];
  int q0 = (int)rintf(v.x * s); q0 = q0 < -1 ? -1 : (q0 > 1 ? 1 : q0);
  int q1 = (int)rintf(v.y * s); q1 = q1 < -1 ? -1 : (q1 > 1 ? 1 : q1);
  int q2 = (int)rintf(v.z * s); q2 = q2 < -1 ? -1 : (q2 > 1 ? 1 : q2);
  int q3 = (int)rintf(v.w * s); q3 = q3 < -1 ? -1 : (q3 > 1 ? 1 : q3);
  ((int*)wq)[i] = (q0 & 255) | ((q1 & 255) << 8) | ((q2 & 255) << 16) | ((q3 & 255) << 24);
}

// ---- per-token activation quant of x ----
__global__ __launch_bounds__(256) void act_quant_x_k(const float* __restrict__ x,
                                                     int8_t* __restrict__ xq,
                                                     float* __restrict__ inv_sx) {
  const int t = threadIdx.x;
  const long row = blockIdx.x;
  const float4* xr = (const float4*)(x + row * DM);
  float4 v0 = xr[t * 2], v1 = xr[t * 2 + 1];
  float m = fmaxf(fmaxf(fmaxf(fabsf(v0.x), fabsf(v0.y)), fmaxf(fabsf(v0.z), fabsf(v0.w))),
                  fmaxf(fmaxf(fabsf(v1.x), fabsf(v1.y)), fmaxf(fabsf(v1.z), fabsf(v1.w))));
#pragma unroll
  for (int d = 1; d < 64; d <<= 1) m = fmaxf(m, __shfl_xor(m, d, 64));
  __shared__ float wm[4];
  if ((t & 63) == 0) wm[t >> 6] = m;
  __syncthreads();
  m = fmaxf(fmaxf(wm[0], wm[1]), fmaxf(wm[2], wm[3]));
  const float scale = 127.0f / fmaxf(m, 1e-5f);
  if (t == 0) inv_sx[row] = 1.0f / scale;
  float vv[8] = {v0.x, v0.y, v0.z, v0.w, v1.x, v1.y, v1.z, v1.w};
  int q[8];
#pragma unroll
  for (int j = 0; j < 8; ++j) {
    int qq = (int)rintf(vv[j] * scale);
    q[j] = qq < -128 ? -128 : (qq > 127 ? 127 : qq);
  }
  int lo = (q[0] & 255) | ((q[1] & 255) << 8) | ((q[2] & 255) << 16) | ((q[3] & 255) << 24);
  int hi = (q[4] & 255) | ((q[5] & 255) << 8) | ((q[6] & 255) << 16) | ((q[7] & 255) << 24);
  ((int2*)(xq + row * DM))[t] = make_int2(lo, hi);
}

// ---- cluster: 16 MFMA (4m x 2n x 2ks), ks-outer so same-acc writes are 8 apart
template <int MO, int NO>
__device__ __forceinline__ void cluster(const v4i (&af)[4][2], const v4i (&bf)[2][2],
                                        v4i (&acc)[8][4]) {
  __builtin_amdgcn_s_setprio(1);
#pragma unroll
  for (int ks = 0; ks < 2; ++ks)
#pragma unroll
    for (int m = 0; m < 4; ++m)
#pragma unroll
      for (int n = 0; n < 2; ++n)
        acc[MO + m][NO + n] = __builtin_amdgcn_mfma_i32_16x16x64_i8(
            af[m][ks], bf[n][ks], acc[MO + m][NO + n], 0, 0, 0);
  __builtin_amdgcn_s_setprio(0);
}

// ---- int8 GEMM, 256x256 tile, BK=128B, 8 waves 2x4, register-pipelined ----
// XCD chunk -> 8by x 4bx supertile remap (proven: FETCH 540->197MB).
// EPI==1: clamp -> LDS-coalesce -> y16 stores ONLY (silu/rowmax moved to quant_h).
template <int K, int N, int EPI>
__global__ __launch_bounds__(512, 2) void gemm8_i8_k(
    const int8_t* __restrict__ A, const int8_t* __restrict__ B,
    const float* __restrict__ rowInv, const float* __restrict__ invswp,
    short* __restrict__ Y16, float* __restrict__ Out) {
  constexpr int NT = K / 128;
  constexpr int NBX = N / 256;
  constexpr int NSTX = NBX / 4;
  __shared__ __align__(16) uint8_t lds[131072];

  const int t = threadIdx.x;
  const int wave = t >> 6;
  const int lane = t & 63;
  const int wr = wave >> 2;   // 0..1
  const int wc = wave & 3;    // 0..3
  const int l15 = lane & 15, l4 = lane >> 4;

  // XCD chunk, then 8x4 supertile order inside each chunk (cpx % 32 == 0)
  const int cpx = (int)gridDim.x >> 3;
  const int bid0 = blockIdx.x;
  const int bid = (bid0 & 7) * cpx + (bid0 >> 3);
  const int st = bid >> 5, u = bid & 31;
  const int by = (st / NSTX) * 8 + (u >> 2);
  const int bx = (st % NSTX) * 4 + (u & 3);
  const long arow0 = (long)by * 256;
  const long bcol0 = (long)bx * 256;

  const int8_t* Ablk = A + arow0 * K;
  const int8_t* Bblk = B + bcol0 * K;

  const int srow = t >> 3;
  const int scol = ((t & 7) ^ (srow & 7)) << 4;

  const int rAo = (wr * 128 + l15) * 128;
  const int rBo = (wc * 64 + l15) * 128;
  const int sw = (l15 & 7) << 4;
  const int cc0 = (l4 * 16) ^ sw;
  const int cc1 = (64 | (l4 * 16)) ^ sw;

  v4i acc[8][4] = {};
  v4i a_lo[4][2], a_hi[4][2], b_lo[2][2], b_hi[2][2];

#define STAGE(ktile_, part_)                                                      \
  do {                                                                            \
    const int kk = (ktile_);                                                      \
    if (kk < NT) {                                                                \
      uint8_t* d0 = lds + ((kk & 1) << 16) + ((part_) << 14) + (wave << 10);      \
      const int8_t* sp = ((part_) < 2) ? Ablk : Bblk;                             \
      const int8_t* s0 =                                                          \
          sp + (long)((((part_) & 1) << 7) + srow) * K + ((long)kk << 7) + scol;  \
      gload_lds16(s0, d0);                                                        \
      gload_lds16(s0 + ((long)K << 6), d0 + 8192);                                \
    }                                                                             \
  } while (0)

#define LGKM0 asm volatile("s_waitcnt lgkmcnt(0)" ::: "memory"); \
              __builtin_amdgcn_sched_barrier(0)
#define SB    __builtin_amdgcn_sched_barrier(0)

  STAGE(0, 0); STAGE(0, 1); STAGE(0, 2); STAGE(0, 3);
  STAGE(1, 0); STAGE(1, 1);
  asm volatile("s_waitcnt vmcnt(4)" ::: "memory");
  __builtin_amdgcn_s_barrier();

  for (int kt = 0; kt < NT; ++kt) {
    const uint8_t* sA = lds + ((kt & 1) << 16);
    const uint8_t* sB = sA + 32768;

#pragma unroll
    for (int m = 0; m < 4; ++m) {
      a_lo[m][0] = *(const v4i*)(sA + rAo + m * 2048 + cc0);
      a_lo[m][1] = *(const v4i*)(sA + rAo + m * 2048 + cc1);
    }
#pragma unroll
    for (int n = 0; n < 2; ++n) {
      b_lo[n][0] = *(const v4i*)(sB + rBo + n * 2048 + cc0);
      b_lo[n][1] = *(const v4i*)(sB + rBo + n * 2048 + cc1);
    }
    STAGE(kt + 1, 2);
    LGKM0;
#pragma unroll
    for (int m = 0; m < 4; ++m) {
      a_hi[m][0] = *(const v4i*)(sA + rAo + (m + 4) * 2048 + cc0);
      a_hi[m][1] = *(const v4i*)(sA + rAo + (m + 4) * 2048 + cc1);
    }
    STAGE(kt + 1, 3);
    SB;
    cluster<0, 0>(a_lo, b_lo, acc);
    LGKM0;
#pragma unroll
    for (int n = 0; n < 2; ++n) {
      b_hi[n][0] = *(const v4i*)(sB + rBo + (n + 2) * 2048 + cc0);
      b_hi[n][1] = *(const v4i*)(sB + rBo + (n + 2) * 2048 + cc1);
    }
    __builtin_amdgcn_s_barrier();
    STAGE(kt + 2, 0);
    SB;
    cluster<4, 0>(a_hi, b_lo, acc);
    LGKM0;
    STAGE(kt + 2, 1);
    SB;
    cluster<0, 2>(a_lo, b_hi, acc);
    cluster<4, 2>(a_hi, b_hi, acc);
    if (kt < NT - 2) {
      asm volatile("s_waitcnt vmcnt(4)" ::: "memory");
    } else if (kt == NT - 2) {
      asm volatile("s_waitcnt vmcnt(0)" ::: "memory");
    }
    __builtin_amdgcn_s_barrier();
  }

  if constexpr (EPI == 1) {
    // integer-only epilogue: clamp -> LDS short[256][256] (XOR swizzle) -> 16B stores
    __syncthreads();
#pragma unroll
    for (int mi = 0; mi < 8; ++mi) {
#pragma unroll
      for (int r = 0; r < 4; ++r) {
        const int row = wr * 128 + mi * 16 + l4 * 4 + r;
#pragma unroll
        for (int ni = 0; ni < 4; ++ni) {
          int yi = acc[mi][ni][r];
          int ys = yi < -32767 ? -32767 : (yi > 32767 ? 32767 : yi);
          const int col = wc * 64 + ni * 16 + l15;
          *(short*)(lds + ((row * 512 + col * 2) ^ ((row & 7) << 4))) = (short)ys;
        }
      }
    }
    __syncthreads();
    const int row = t >> 1;
    const int half = t & 1;
    short* gp = Y16 + (arow0 + row) * (long)DF + bcol0 + half * 128;
#pragma unroll
    for (int i = 0; i < 16; ++i) {
      v8s yv = *(const v8s*)(lds + ((row * 512 + half * 256 + i * 16) ^ ((row & 7) << 4)));
      *(v8s*)(gp + i * 8) = yv;
    }
  } else {
    const float invsw = invswp[0];
#pragma unroll
    for (int mi = 0; mi < 8; ++mi) {
#pragma unroll
      for (int r = 0; r < 4; ++r) {
        const long grow = arow0 + wr * 128 + mi * 16 + l4 * 4 + r;
        const float c2 = rowInv[grow] * invsw;
#pragma unroll
        for (int ni = 0; ni < 4; ++ni)
          Out[grow * N + bcol0 + wc * 64 + ni * 16 + l15] = (float)acc[mi][ni][r] * c2;
      }
    }
  }
#undef STAGE
#undef LGKM0
#undef SB
}

// ---- quant_h: two-pass per row. Pass 1: silu into 32 registers + block max.
// Pass 2: quantize from registers. Bit-identical h expression to before.
__global__ __launch_bounds__(256) void quant_h_k(const short* __restrict__ Y16,
                                                 const float* __restrict__ inv_sx,
                                                 const float* __restrict__ sc,
                                                 int8_t* __restrict__ hq,
                                                 float* __restrict__ inv_sh) {
  const int t = threadIdx.x;
  const long row = blockIdx.x;
  const float c1 = inv_sx[row] * sc[1];
  const v8s* yp = (const v8s*)(Y16 + row * DF);
  float h[32];
  float mx = 0.f;
#pragma unroll
  for (int b = 0; b < 4; ++b) {
    v8s s8 = yp[b * 256 + t];
#pragma unroll
    for (int j = 0; j < 8; ++j) {
      float hv = silu_f((float)s8[j] * c1);
      h[b * 8 + j] = hv;
      mx = fmaxf(mx, fabsf(hv));
    }
  }
#pragma unroll
  for (int d = 1; d < 64; d <<= 1) mx = fmaxf(mx, __shfl_xor(mx, d, 64));
  __shared__ float wm[4];
  if ((t & 63) == 0) wm[t >> 6] = mx;
  __syncthreads();
  const float m = fmaxf(fmaxf(wm[0], wm[1]), fmaxf(wm[2], wm[3]));
  const float scale = 127.0f / fmaxf(m, 1e-5f);
  if (t == 0) inv_sh[row] = 1.0f / scale;
  int2* op = (int2*)(hq + row * DF);
#pragma unroll
  for (int b = 0; b < 4; ++b) {
    int q[8];
#pragma unroll
    for (int j = 0; j < 8; ++j) {
      int qq = (int)rintf(h[b * 8 + j] * scale);
      q[j] = qq < -128 ? -128 : (qq > 127 ? 127 : qq);
    }
    int lo = (q[0] & 255) | ((q[1] & 255) << 8) | ((q[2] & 255) << 16) | ((q[3] & 255) << 24);
    int hi = (q[4] & 255) | ((q[5] & 255) << 8) | ((q[6] & 255) << 16) | ((q[7] & 255) << 24);
    op[b * 256 + t] = make_int2(lo, hi);
  }
}

extern "C" void kernel_launch(void* const* d_in, const int* in_sizes, int n_in,
                              void* d_out, int out_size, void* d_ws, size_t ws_size,
                              hipStream_t stream) {
  const float* x = (const float*)d_in[0];
  const float* W1 = (const float*)d_in[1];
  const float* W2 = (const float*)d_in[2];
  float* out = (float*)d_out;

  uint8_t* w = (uint8_t*)d_ws;
  float* sc = (float*)(w + 0);
  float* p1 = (float*)(w + 256);
  float* p2 = (float*)(w + 256 + 4096);
  float* inv_sx = (float*)(w + 8448);
  float* inv_sh = (float*)(w + 8448 + 65536);
  uint8_t* w1q = w + 8448 + 131072 + 4194304;
  uint8_t* w2q = w1q + 16777216;
  uint8_t* xq = w2q + 16777216;
  uint8_t* hq = xq + 33554432;
  short* y16 = (short*)(hq + 134217728);

  abs_sum_k<<<1024, 256, 0, stream>>>(W1, p1);
  abs_sum_k<<<1024, 256, 0, stream>>>(W2, p2);
  finalize_scales_k<<<2, 256, 0, stream>>>(p1, p2, sc);
  tern_quant_k<<<16384, 256, 0, stream>>>(W1, (int8_t*)w1q, sc + 0);
  tern_quant_k<<<16384, 256, 0, stream>>>(W2, (int8_t*)w2q, sc + 2);
  act_quant_x_k<<<16384, 256, 0, stream>>>(x, (int8_t*)xq, inv_sx);
  // GEMM1: [16384,2048] x [8192,2048]^T -> y16 (integer-only epilogue)
  gemm8_i8_k<2048, 8192, 1><<<2048, 512, 0, stream>>>(
      (const int8_t*)xq, (const int8_t*)w1q, nullptr, nullptr, y16, nullptr);
  quant_h_k<<<16384, 256, 0, stream>>>(y16, inv_sx, sc, (int8_t*)hq, inv_sh);
  // GEMM2: [16384,8192] x [2048,8192]^T -> out
  gemm8_i8_k<8192, 2048, 0><<<512, 512, 0, stream>>>(
      (const int8_t*)hq, (const int8_t*)w2q, inv_sh, sc + 3, nullptr, out);
}